// Round 6
// baseline (572.836 us; speedup 1.0000x reference)
//
#include <hip/hip_runtime.h>

// (B, D, H, W, K) = (64, 256, 32, 32, 512)
#define DIM    256
#define KCODE  512
#define NPOS   1024
#define BATCH  64
#define NPB    128           // positions per block
#define KD     16            // dims per K-step (32x32x16 MFMA)
#define KSTEPS (DIM / KD)    // 16
#define EPS    0.05f
#define ENT    8

using bf16x8 = __attribute__((ext_vector_type(8))) __bf16;
using bf16x4 = __attribute__((ext_vector_type(4))) __bf16;
using f32x16 = __attribute__((ext_vector_type(16))) float;

// workspace layout (bytes)
#define WS_CNT   0
#define WS_ESQ   64
#define WS_WPK   4096
#define WS_WT    (4096 + 512 * 1024)
#define WS_LIST  (4096 + 1024 * 1024)

// swizzle: XOR byte-bits[5:4] of the 16B slot with row-bits[2:1]
#define SWZ(r) ((((r) >> 1) & 3) << 4)

// ---------------- merged prep: wpack | wT transpose | e_sq | cnt ----------------
__global__ __launch_bounds__(256) void prep(const float* __restrict__ w,
                                            unsigned char* __restrict__ wpk,
                                            float* __restrict__ wT,
                                            float* __restrict__ esq,
                                            int* __restrict__ cnt) {
    __shared__ float ts[32][33];
    __shared__ double sh[8][32];
    const int tid = threadIdx.x;
    const int blk = blockIdx.x;
    if (blk < 64) {
        // pack w into frag-ready swizzled hi|lo bf16 image
        int gid = blk * 256 + tid;     // 16384 = 16t * 2g * 512c
        int c = gid & 511;
        int r = gid >> 9;
        int t = r >> 1, g = r & 1;
        bf16x8 hi, lo;
#pragma unroll
        for (int j = 0; j < 8; ++j) {
            float v = w[(16 * t + 8 * g + j) * KCODE + c];
            __bf16 h = (__bf16)v;
            hi[j] = h;
            lo[j] = (__bf16)(v - (float)h);
        }
        unsigned char* row = wpk + ((size_t)t * KCODE + c) * 64;
        int sw = SWZ(c);
        *(bf16x8*)(row + ((g * 16) ^ sw))       = hi;
        *(bf16x8*)(row + (((2 + g) * 16) ^ sw)) = lo;
    } else if (blk < 192) {
        // transpose w[D][K] -> wT[K][D], 32x32 LDS tiles
        int tt = blk - 64;             // 128 tiles = 16 k-tiles x 8 d-tiles
        int kt = tt >> 3, dt = tt & 7;
        int c = tid & 31, rl = tid >> 5;   // 8 row-groups of 4
#pragma unroll
        for (int r = 0; r < 4; ++r) {
            int dloc = rl * 4 + r;
            ts[dloc][c] = w[(dt * 32 + dloc) * KCODE + kt * 32 + c];
        }
        __syncthreads();
#pragma unroll
        for (int r = 0; r < 4; ++r) {
            int kloc = rl * 4 + r;
            wT[(size_t)(kt * 32 + kloc) * DIM + dt * 32 + c] = ts[c][kloc];
        }
    } else if (blk < 208) {
        // e_sq in fp64
        int idx = blk - 192;
        int code = idx * 32 + (tid & 31);
        int sl = tid >> 5;
        double s = 0.0;
        for (int d = sl * 32; d < sl * 32 + 32; ++d) {
            double v = (double)w[d * KCODE + code];
            s = fma(v, v, s);
        }
        sh[sl][tid & 31] = s;
        __syncthreads();
        if (tid < 32) {
            double t = 0.0;
            for (int i = 0; i < 8; ++i) t += sh[i][tid];
            esq[idx * 32 + tid] = (float)t;
        }
    } else {
        if (tid == 0) *cnt = 0;
    }
}

// ---------------- main: 3-pass split-bf16 MFMA, single-buffer, 3 blocks/CU ----------------
__global__ __launch_bounds__(512, 4) void vq_main(
    const float* __restrict__ x, const unsigned char* __restrict__ wpk,
    const float* __restrict__ esq, const float* __restrict__ wT,
    float* __restrict__ quant, float* __restrict__ argm,
    int* __restrict__ cnt, int* __restrict__ list) {

    // manual LDS partition (43008 B -> 3 blocks/CU)
    __shared__ __align__(128) unsigned char smem[43008];
    unsigned char* At = smem;                     // [0, 32768)   A tile (512 codes x 64B)
    unsigned char* Bt = smem + 32768;             // [32768,40960) B tile (128 pos x 64B)
    float* esq_s  = (float*)(smem + 40960);       // [40960,43008) e_sq (live whole kernel)
    // epilogue overlays (valid only after post-loop barrier):
    float* red1   = (float*)smem;                 // 8*128*4 = 4096
    float* red2   = (float*)(smem + 4096);
    int*   redi   = (int*)(smem + 8192);
    float* qt     = (float*)smem;                 // 128*65*4 = 33280 (quant phase)
    float* bestv  = (float*)(smem + 36864);       // in Bt region
    int*   idxbuf = (int*)(smem + 37376);         // in Bt region

    const int tid  = threadIdx.x;
    const int wv   = tid >> 6;
    const int lane = tid & 63;
    const int L    = lane & 31;
    const int h5   = lane >> 5;

    const int p0 = blockIdx.x * NPB;
    const int b  = p0 >> 10;
    const int n0 = p0 & (NPOS - 1);

    // B-staging identity: pos + 4-dim slice q
    const int pos = tid & 127;
    const int q   = tid >> 7;           // 0..3
    const int gq  = q >> 1, o8 = (q & 1) * 8;
    const int swp = SWZ(pos);

    esq_s[tid] = esq[tid];

    f32x16 acc[2][4] = {};

#define STAGE_A(t)                                                                \
    {                                                                             \
        const unsigned char* gA = wpk + (size_t)(t) * (KCODE * 64);               \
        _Pragma("unroll")                                                         \
        for (int r = 0; r < 4; ++r)                                               \
            __builtin_amdgcn_global_load_lds(                                     \
                (const __attribute__((address_space(1))) void*)(gA + r * 8192 + tid * 16), \
                (__attribute__((address_space(3))) void*)(At + r * 8192 + tid * 16),       \
                16, 0, 0);                                                        \
    }

#define B_LOAD(t)                                                                 \
    {                                                                             \
        const float* xp = x + ((size_t)b * DIM + (t) * KD + q * 4) * NPOS + n0 + pos; \
        bv0 = xp[0]; bv1 = xp[NPOS]; bv2 = xp[2 * NPOS]; bv3 = xp[3 * NPOS];      \
    }

#define B_WRITE()                                                                 \
    {                                                                             \
        __bf16 h0 = (__bf16)bv0, h1 = (__bf16)bv1, h2 = (__bf16)bv2, h3 = (__bf16)bv3; \
        bf16x4 hv = {h0, h1, h2, h3};                                             \
        bf16x4 lv = {(__bf16)(bv0 - (float)h0), (__bf16)(bv1 - (float)h1),        \
                     (__bf16)(bv2 - (float)h2), (__bf16)(bv3 - (float)h3)};       \
        unsigned char* row = Bt + pos * 64;                                       \
        *(bf16x4*)(row + (((gq) << 4) ^ swp) + o8)     = hv;                      \
        *(bf16x4*)(row + (((2 + gq) << 4) ^ swp) + o8) = lv;                      \
    }

#define COMPUTE()                                                                 \
    {                                                                             \
        bf16x8 ah[2], al[2];                                                      \
        _Pragma("unroll")                                                         \
        for (int fm = 0; fm < 2; ++fm) {                                          \
            int ar = wv * 64 + fm * 32 + L;                                       \
            const unsigned char* rp = At + ar * 64;                               \
            int sw = SWZ(ar);                                                     \
            ah[fm] = *(const bf16x8*)(rp + ((h5 << 4) ^ sw));                     \
            al[fm] = *(const bf16x8*)(rp + (((2 + h5) << 4) ^ sw));               \
        }                                                                         \
        __builtin_amdgcn_s_setprio(1);                                            \
        _Pragma("unroll")                                                         \
        for (int fn = 0; fn < 4; ++fn) {                                          \
            int pr = fn * 32 + L;                                                 \
            const unsigned char* rp = Bt + pr * 64;                               \
            int sw = SWZ(pr);                                                     \
            bf16x8 bh = *(const bf16x8*)(rp + ((h5 << 4) ^ sw));                  \
            bf16x8 bl = *(const bf16x8*)(rp + (((2 + h5) << 4) ^ sw));            \
            _Pragma("unroll")                                                     \
            for (int fm = 0; fm < 2; ++fm) {                                      \
                acc[fm][fn] = __builtin_amdgcn_mfma_f32_32x32x16_bf16(ah[fm], bh, acc[fm][fn], 0, 0, 0); \
                acc[fm][fn] = __builtin_amdgcn_mfma_f32_32x32x16_bf16(ah[fm], bl, acc[fm][fn], 0, 0, 0); \
                acc[fm][fn] = __builtin_amdgcn_mfma_f32_32x32x16_bf16(al[fm], bh, acc[fm][fn], 0, 0, 0); \
            }                                                                     \
        }                                                                         \
        __builtin_amdgcn_s_setprio(0);                                            \
    }

    float bv0, bv1, bv2, bv3;
    B_LOAD(0);

    for (int t = 0; t < KSTEPS; ++t) {
        __syncthreads();                 // previous COMPUTE done; At/Bt writable
        STAGE_A(t);                      // async DMA into At
        B_WRITE();                       // ds_write from regs loaded last iter
        B_LOAD(t + 1 < KSTEPS ? t + 1 : KSTEPS - 1);  // next-step x under this compute
        asm volatile("s_waitcnt vmcnt(0)" ::: "memory");
        __syncthreads();
        COMPUTE();
    }
    __syncthreads();                     // all LDS reads done -> overlays safe

    // ---------------- epilogue: score, per-lane top-2, argmin ----------------
    float v1[4] = {3.4e38f, 3.4e38f, 3.4e38f, 3.4e38f};
    float v2[4] = {3.4e38f, 3.4e38f, 3.4e38f, 3.4e38f};
#pragma unroll
    for (int fm = 0; fm < 2; ++fm)
#pragma unroll
        for (int r = 0; r < 16; ++r) {
            int code = wv * 64 + fm * 32 + (r & 3) + 8 * (r >> 2) + 4 * h5;
            float e = esq_s[code];
#pragma unroll
            for (int fn = 0; fn < 4; ++fn) {
                float s = fmaf(-2.f, acc[fm][fn][r], e);
                acc[fm][fn][r] = s;
                float lo_ = fminf(s, v1[fn]);
                float hi_ = fmaxf(s, v1[fn]);
                v1[fn] = lo_;
                v2[fn] = fminf(v2[fn], hi_);
            }
        }
#pragma unroll
    for (int fn = 0; fn < 4; ++fn) {
        float o1 = __shfl_xor(v1[fn], 32, 64);
        float o2 = __shfl_xor(v2[fn], 32, 64);
        float mn = fminf(v1[fn], o1);
        float mx = fmaxf(v1[fn], o1);
        v1[fn] = mn;
        v2[fn] = fminf(fminf(v2[fn], o2), mx);
        if (h5 == 0) { red1[wv * NPB + fn * 32 + L] = v1[fn]; red2[wv * NPB + fn * 32 + L] = v2[fn]; }
    }
    __syncthreads();
    float gapv = 0.f;
    if (tid < NPB) {
        float g1 = red1[tid], g2 = red2[tid];
#pragma unroll
        for (int wvi = 1; wvi < 8; ++wvi) {
            float a1 = red1[wvi * NPB + tid], a2 = red2[wvi * NPB + tid];
            float mn = fminf(g1, a1), mx = fmaxf(g1, a1);
            g1 = mn; g2 = fminf(fminf(g2, a2), mx);
        }
        bestv[tid] = g1;
        gapv = g2 - g1;
    }
    __syncthreads();
    // rescan for argmin index (min code among exact matches)
#pragma unroll
    for (int fn = 0; fn < 4; ++fn) {
        float tgt = bestv[fn * 32 + L];
        int cand = 0x7FFFFFFF;
#pragma unroll
        for (int fm = 0; fm < 2; ++fm)
#pragma unroll
            for (int r = 0; r < 16; ++r) {
                int code = wv * 64 + fm * 32 + (r & 3) + 8 * (r >> 2) + 4 * h5;
                if (acc[fm][fn][r] == tgt) cand = min(cand, code);
            }
        int oc = __shfl_xor(cand, 32, 64);
        cand = min(cand, oc);
        if (h5 == 0) redi[wv * NPB + fn * 32 + L] = cand;
    }
    __syncthreads();
    if (tid < NPB) {
        int bi = redi[tid];
#pragma unroll
        for (int wvi = 1; wvi < 8; ++wvi) bi = min(bi, redi[wvi * NPB + tid]);
        idxbuf[tid] = bi;
        argm[(size_t)b * NPOS + n0 + tid] = (float)bi;
        if (gapv < EPS) {
            int slot = atomicAdd(cnt, 1);
            list[slot] = p0 + tid;
        }
    }
    __syncthreads();

    // ---------------- quant write: coalesced row-copies via padded LDS tile ----------------
    for (int ch = 0; ch < 4; ++ch) {             // 4 chunks of 64 dims
        // copy-in: one wave copies one code row slice (256B, fully coalesced)
#pragma unroll
        for (int it = 0; it < 16; ++it) {
            int pp = it * 8 + wv;
            int bi = idxbuf[pp];
            qt[pp * 65 + lane] = wT[(size_t)bi * DIM + ch * 64 + lane];
        }
        __syncthreads();
        // copy-out: d-major coalesced stores over positions
#pragma unroll
        for (int i = 0; i < 16; ++i) {
            int d = ch * 64 + i * 4 + q;
            quant[((size_t)b * DIM + d) * NPOS + n0 + pos] = qt[pos * 65 + i * 4 + q];
        }
        __syncthreads();
    }
}

// ---------------- refine: exact fp64 distances for near-tie positions ----------------
__global__ __launch_bounds__(256) void refine(const float* __restrict__ x,
                                              const float* __restrict__ w,
                                              float* __restrict__ quant,
                                              float* __restrict__ argm,
                                              const int* __restrict__ cnt,
                                              const int* __restrict__ list) {
    __shared__ float xs[ENT][DIM];
    __shared__ double dv[256];
    __shared__ int    di[256];
    const int tid = threadIdx.x;
    const int n = *cnt;
    for (int base = blockIdx.x * ENT; base < n; base += gridDim.x * ENT) {
        int nk = min(ENT, n - base);
        for (int e = 0; e < nk; ++e) {
            int p = list[base + e];
            xs[e][tid] = x[((size_t)(p >> 10) * DIM + tid) * NPOS + (p & (NPOS - 1))];
        }
        __syncthreads();
        double a0[ENT], a1[ENT], sw0 = 0.0, sw1 = 0.0;
#pragma unroll
        for (int e = 0; e < ENT; ++e) { a0[e] = 0.0; a1[e] = 0.0; }
        for (int d = 0; d < DIM; ++d) {
            double w0 = (double)w[d * KCODE + tid];
            double w1 = (double)w[d * KCODE + tid + 256];
            sw0 = fma(w0, w0, sw0);
            sw1 = fma(w1, w1, sw1);
#pragma unroll
            for (int e = 0; e < ENT; ++e) {
                double xv = (double)xs[e][d];
                a0[e] = fma(w0, xv, a0[e]);
                a1[e] = fma(w1, xv, a1[e]);
            }
        }
        for (int e = 0; e < nk; ++e) {
            double d0 = sw0 - 2.0 * a0[e];
            double d1 = sw1 - 2.0 * a1[e];
            double bvv; int bi;
            if (d1 < d0) { bvv = d1; bi = tid + 256; } else { bvv = d0; bi = tid; }
            dv[tid] = bvv; di[tid] = bi;
            __syncthreads();
            for (int off = 128; off > 0; off >>= 1) {
                if (tid < off) {
                    double ov = dv[tid + off]; int oi = di[tid + off];
                    if (ov < dv[tid] || (ov == dv[tid] && oi < di[tid])) { dv[tid] = ov; di[tid] = oi; }
                }
                __syncthreads();
            }
            int p = list[base + e];
            int bsel = di[0];
            size_t pb = (size_t)(p >> 10), pn = (size_t)(p & (NPOS - 1));
            if (tid == 0) argm[pb * NPOS + pn] = (float)bsel;
            quant[(pb * DIM + tid) * NPOS + pn] = w[tid * KCODE + bsel];
            __syncthreads();
        }
        __syncthreads();
    }
}

extern "C" void kernel_launch(void* const* d_in, const int* in_sizes, int n_in,
                              void* d_out, int out_size, void* d_ws, size_t ws_size,
                              hipStream_t stream) {
    (void)in_sizes; (void)n_in; (void)out_size; (void)ws_size;
    const float* x = (const float*)d_in[0];
    const float* w = (const float*)d_in[1];
    float* quant = (float*)d_out;
    float* argm  = quant + (size_t)BATCH * DIM * NPOS;
    char* ws = (char*)d_ws;
    int*   cnt = (int*)(ws + WS_CNT);
    float* esq = (float*)(ws + WS_ESQ);
    unsigned char* wpk = (unsigned char*)(ws + WS_WPK);
    float* wT  = (float*)(ws + WS_WT);
    int*   list = (int*)(ws + WS_LIST);

    prep<<<209, 256, 0, stream>>>(w, wpk, wT, esq, cnt);
    vq_main<<<(BATCH * NPOS) / NPB, 512, 0, stream>>>(x, wpk, esq, wT, quant, argm, cnt, list);
    refine<<<256, 256, 0, stream>>>(x, w, quant, argm, cnt, list);
}

// Round 7
// 122.956 us; speedup vs baseline: 4.6589x; 4.6589x over previous
//
#include <hip/hip_runtime.h>

// (B, D, H, W, K) = (64, 256, 32, 32, 512)
#define DIM    256
#define KCODE  512
#define NPOS   1024
#define BATCH  64
#define NPB    128           // positions per block
#define KSTEPS 16            // 16 dims per step (32x32x16 f16 MFMA)
#define EPS    0.05f
#define ENT    8

using f16x8  = __attribute__((ext_vector_type(8))) _Float16;
using f32x16 = __attribute__((ext_vector_type(16))) float;

// workspace layout (bytes)
#define WS_CNT   0
#define WS_ESQ   64
#define WS_WPK   4096                    // 512 KB f16 2-digit packed codebook
#define WS_WT    (4096 + 524288)         // 512 KB wT[K][D] f32
#define WS_LIST  (4096 + 1048576)        // refine list

// ---------------- prep: wpk frag-pack | wT transpose | e_sq fp64 | cnt ----------------
// wpk chunk per gidx = t*32 + cg*2 + dg : 64 lanes x 16 B; lane holds
// A[m = lane&31][k = (lane>>5)*8 + j] = w_digit[t*16 + (lane>>5)*8 + j][cg*32 + (lane&31)]
__global__ __launch_bounds__(256) void prep(const float* __restrict__ w,
                                            _Float16* __restrict__ wpk,
                                            float* __restrict__ wT,
                                            float* __restrict__ esq,
                                            int* __restrict__ cnt) {
    __shared__ float ts[32][33];
    __shared__ double sh[8][32];
    const int tid = threadIdx.x;
    const int blk = blockIdx.x;
    if (blk < 128) {
        int gidx = blk * 4 + (tid >> 6);          // 0..511
        int dg = gidx & 1, cg = (gidx >> 1) & 15, t = gidx >> 5;
        int lane = tid & 63, L = lane & 31, h5 = lane >> 5;
        f16x8 out;
#pragma unroll
        for (int j = 0; j < 8; ++j) {
            float v = w[(t * 16 + h5 * 8 + j) * KCODE + cg * 32 + L];
            _Float16 h = (_Float16)v;
            out[j] = dg ? (_Float16)(v - (float)h) : h;
        }
        *(f16x8*)(wpk + (size_t)gidx * 512 + lane * 8) = out;
    } else if (blk < 256) {
        // transpose w[D][K] -> wT[K][D], 32x32 LDS tiles
        int tt = blk - 128;            // 128 tiles = 16 k-tiles x 8 d-tiles
        int kt = tt >> 3, dt = tt & 7;
        int c = tid & 31, rl = tid >> 5;
#pragma unroll
        for (int r = 0; r < 4; ++r) {
            int dloc = rl * 4 + r;
            ts[dloc][c] = w[(dt * 32 + dloc) * KCODE + kt * 32 + c];
        }
        __syncthreads();
#pragma unroll
        for (int r = 0; r < 4; ++r) {
            int kloc = rl * 4 + r;
            wT[(size_t)(kt * 32 + kloc) * DIM + dt * 32 + c] = ts[c][kloc];
        }
    } else if (blk < 272) {
        int idx = blk - 256;
        int code = idx * 32 + (tid & 31);
        int sl = tid >> 5;
        double s = 0.0;
        for (int d = sl * 32; d < sl * 32 + 32; ++d) {
            double v = (double)w[d * KCODE + code];
            s = fma(v, v, s);
        }
        sh[sl][tid & 31] = s;
        __syncthreads();
        if (tid < 32) {
            double t = 0.0;
            for (int i = 0; i < 8; ++i) t += sh[i][tid];
            esq[idx * 32 + tid] = (float)t;
        }
    } else {
        if (tid == 0) *cnt = 0;
    }
}

// ---------------- main: B LDS-resident, A streamed to regs, 2-pass f16 MFMA ----------------
__global__ __launch_bounds__(512, 2) void vq_main(
    const float* __restrict__ x, const _Float16* __restrict__ wpk,
    const float* __restrict__ esq, const float* __restrict__ wT,
    float* __restrict__ quant, float* __restrict__ argm,
    int* __restrict__ cnt, int* __restrict__ list) {

    // LDS: Bt [16t][2h5][128pos][16B] = 64 KB, resident through K-loop;
    // esq_s 2 KB; epilogue overlays live inside Bt after the loop.
    __shared__ __align__(128) unsigned char smem[67584];
    unsigned char* Bt = smem;                    // 64 KB
    float* esq_s  = (float*)(smem + 65536);      // 2 KB
    float* red1   = (float*)smem;                // 8*128*4 = 4 KB
    float* red2   = (float*)(smem + 4096);       // 4 KB
    int*   redi   = (int*)(smem + 8192);         // 4 KB
    float* qt     = (float*)(smem + 12288);      // 128*65*4 = 33280
    float* bestv  = (float*)(smem + 49152);      // 512 B
    int*   idxbuf = (int*)(smem + 49664);        // 512 B

    const int tid  = threadIdx.x;
    const int wv   = tid >> 6;        // wave = code group: codes [wv*64, wv*64+64)
    const int lane = tid & 63;
    const int L    = lane & 31;
    const int h5   = lane >> 5;

    const int p0 = blockIdx.x * NPB;
    const int b  = p0 >> 10;
    const int n0 = p0 & (NPOS - 1);

    const int pos = tid & 127;
    const int tg  = tid >> 7;         // 0..3

    esq_s[tid] = esq[tid];

    // ---- stage B once: x f32 -> f16 (1 digit), frag-ready dense layout ----
#pragma unroll
    for (int tt = 0; tt < 4; ++tt) {
        int t = tg * 4 + tt;
#pragma unroll
        for (int hh = 0; hh < 2; ++hh) {
            const float* xp = x + ((size_t)b * DIM + t * 16 + hh * 8) * NPOS + n0 + pos;
            f16x8 v;
#pragma unroll
            for (int j = 0; j < 8; ++j) v[j] = (_Float16)xp[(size_t)j * NPOS];
            *(f16x8*)(Bt + ((t * 2 + hh) * 128 + pos) * 16) = v;
        }
    }
    __syncthreads();

    // ---- K-loop: no barriers, register dataflow only ----
    f32x16 acc[2][4] = {};
    f16x8 Ah[2][2][2];   // [parity][fm][digit] -- static indexing under full unroll

#define LOAD_A(buf, t)                                                            \
    {                                                                             \
        _Pragma("unroll")                                                         \
        for (int fm = 0; fm < 2; ++fm)                                            \
            _Pragma("unroll")                                                     \
            for (int dg = 0; dg < 2; ++dg)                                        \
                Ah[buf][fm][dg] = *(const f16x8*)(                                \
                    wpk + (size_t)((((t) * 16 + wv * 2 + fm) * 2 + dg) * 64 + lane) * 8); \
    }

    LOAD_A(0, 0);
#pragma unroll
    for (int t = 0; t < KSTEPS; ++t) {
        if (t < KSTEPS - 1) LOAD_A((t + 1) & 1, t + 1);
        f16x8 Bf[4];
#pragma unroll
        for (int fn = 0; fn < 4; ++fn)
            Bf[fn] = *(const f16x8*)(Bt + ((t * 2 + h5) * 128 + fn * 32 + L) * 16);
        __builtin_amdgcn_s_setprio(1);
#pragma unroll
        for (int fm = 0; fm < 2; ++fm)
#pragma unroll
            for (int fn = 0; fn < 4; ++fn) {
                acc[fm][fn] = __builtin_amdgcn_mfma_f32_32x32x16_f16(Ah[t & 1][fm][0], Bf[fn], acc[fm][fn], 0, 0, 0);
                acc[fm][fn] = __builtin_amdgcn_mfma_f32_32x32x16_f16(Ah[t & 1][fm][1], Bf[fn], acc[fm][fn], 0, 0, 0);
            }
        __builtin_amdgcn_s_setprio(0);
    }
    __syncthreads();                  // B reads done -> overlays safe

    // ---- epilogue: score = e^2 - 2*cross, per-lane top-2, block argmin ----
    float v1[4] = {3.4e38f, 3.4e38f, 3.4e38f, 3.4e38f};
    float v2[4] = {3.4e38f, 3.4e38f, 3.4e38f, 3.4e38f};
#pragma unroll
    for (int fm = 0; fm < 2; ++fm)
#pragma unroll
        for (int r = 0; r < 16; ++r) {
            int code = wv * 64 + fm * 32 + (r & 3) + 8 * (r >> 2) + 4 * h5;
            float e = esq_s[code];
#pragma unroll
            for (int fn = 0; fn < 4; ++fn) {
                float s = fmaf(-2.f, acc[fm][fn][r], e);
                acc[fm][fn][r] = s;
                float lo_ = fminf(s, v1[fn]);
                float hi_ = fmaxf(s, v1[fn]);
                v1[fn] = lo_;
                v2[fn] = fminf(v2[fn], hi_);
            }
        }
#pragma unroll
    for (int fn = 0; fn < 4; ++fn) {
        float o1 = __shfl_xor(v1[fn], 32, 64);
        float o2 = __shfl_xor(v2[fn], 32, 64);
        float mn = fminf(v1[fn], o1);
        float mx = fmaxf(v1[fn], o1);
        v1[fn] = mn;
        v2[fn] = fminf(fminf(v2[fn], o2), mx);
        if (h5 == 0) { red1[wv * NPB + fn * 32 + L] = v1[fn]; red2[wv * NPB + fn * 32 + L] = v2[fn]; }
    }
    __syncthreads();
    float gapv = 0.f;
    if (tid < NPB) {
        float g1 = red1[tid], g2 = red2[tid];
#pragma unroll
        for (int wvi = 1; wvi < 8; ++wvi) {
            float a1 = red1[wvi * NPB + tid], a2 = red2[wvi * NPB + tid];
            float mn = fminf(g1, a1), mx = fmaxf(g1, a1);
            g1 = mn; g2 = fminf(fminf(g2, a2), mx);
        }
        bestv[tid] = g1;
        gapv = g2 - g1;
    }
    __syncthreads();
#pragma unroll
    for (int fn = 0; fn < 4; ++fn) {
        float tgt = bestv[fn * 32 + L];
        int cand = 0x7FFFFFFF;
#pragma unroll
        for (int fm = 0; fm < 2; ++fm)
#pragma unroll
            for (int r = 0; r < 16; ++r) {
                int code = wv * 64 + fm * 32 + (r & 3) + 8 * (r >> 2) + 4 * h5;
                if (acc[fm][fn][r] == tgt) cand = min(cand, code);
            }
        int oc = __shfl_xor(cand, 32, 64);
        cand = min(cand, oc);
        if (h5 == 0) redi[wv * NPB + fn * 32 + L] = cand;
    }
    __syncthreads();
    if (tid < NPB) {
        int bi = redi[tid];
#pragma unroll
        for (int wvi = 1; wvi < 8; ++wvi) bi = min(bi, redi[wvi * NPB + tid]);
        idxbuf[tid] = bi;
        argm[(size_t)b * NPOS + n0 + tid] = (float)bi;
        if (gapv < EPS) {
            int slot = atomicAdd(cnt, 1);
            list[slot] = p0 + tid;
        }
    }
    __syncthreads();

    // ---- quant write: coalesced wT row-copies via padded LDS tile ----
    for (int ch = 0; ch < 4; ++ch) {
#pragma unroll
        for (int it = 0; it < 16; ++it) {
            int pp = it * 8 + wv;
            int bi = idxbuf[pp];
            qt[pp * 65 + lane] = wT[(size_t)bi * DIM + ch * 64 + lane];
        }
        __syncthreads();
#pragma unroll
        for (int i = 0; i < 16; ++i) {
            int d = ch * 64 + i * 4 + tg;
            quant[((size_t)b * DIM + d) * NPOS + n0 + pos] = qt[pos * 65 + i * 4 + tg];
        }
        __syncthreads();
    }
}

// ---------------- refine: exact fp64 distances for near-tie positions ----------------
__global__ __launch_bounds__(256) void refine(const float* __restrict__ x,
                                              const float* __restrict__ w,
                                              float* __restrict__ quant,
                                              float* __restrict__ argm,
                                              const int* __restrict__ cnt,
                                              const int* __restrict__ list) {
    __shared__ float xs[ENT][DIM];
    __shared__ double dv[256];
    __shared__ int    di[256];
    const int tid = threadIdx.x;
    const int n = *cnt;
    for (int base = blockIdx.x * ENT; base < n; base += gridDim.x * ENT) {
        int nk = min(ENT, n - base);
        for (int e = 0; e < nk; ++e) {
            int p = list[base + e];
            xs[e][tid] = x[((size_t)(p >> 10) * DIM + tid) * NPOS + (p & (NPOS - 1))];
        }
        __syncthreads();
        double a0[ENT], a1[ENT], sw0 = 0.0, sw1 = 0.0;
#pragma unroll
        for (int e = 0; e < ENT; ++e) { a0[e] = 0.0; a1[e] = 0.0; }
        for (int d = 0; d < DIM; ++d) {
            double w0 = (double)w[d * KCODE + tid];
            double w1 = (double)w[d * KCODE + tid + 256];
            sw0 = fma(w0, w0, sw0);
            sw1 = fma(w1, w1, sw1);
#pragma unroll
            for (int e = 0; e < ENT; ++e) {
                double xv = (double)xs[e][d];
                a0[e] = fma(w0, xv, a0[e]);
                a1[e] = fma(w1, xv, a1[e]);
            }
        }
        for (int e = 0; e < nk; ++e) {
            double d0 = sw0 - 2.0 * a0[e];
            double d1 = sw1 - 2.0 * a1[e];
            double bvv; int bi;
            if (d1 < d0) { bvv = d1; bi = tid + 256; } else { bvv = d0; bi = tid; }
            dv[tid] = bvv; di[tid] = bi;
            __syncthreads();
            for (int off = 128; off > 0; off >>= 1) {
                if (tid < off) {
                    double ov = dv[tid + off]; int oi = di[tid + off];
                    if (ov < dv[tid] || (ov == dv[tid] && oi < di[tid])) { dv[tid] = ov; di[tid] = oi; }
                }
                __syncthreads();
            }
            int p = list[base + e];
            int bsel = di[0];
            size_t pb = (size_t)(p >> 10), pn = (size_t)(p & (NPOS - 1));
            if (tid == 0) argm[pb * NPOS + pn] = (float)bsel;
            quant[(pb * DIM + tid) * NPOS + pn] = w[tid * KCODE + bsel];
            __syncthreads();
        }
        __syncthreads();
    }
}

extern "C" void kernel_launch(void* const* d_in, const int* in_sizes, int n_in,
                              void* d_out, int out_size, void* d_ws, size_t ws_size,
                              hipStream_t stream) {
    (void)in_sizes; (void)n_in; (void)out_size; (void)ws_size;
    const float* x = (const float*)d_in[0];
    const float* w = (const float*)d_in[1];
    float* quant = (float*)d_out;
    float* argm  = quant + (size_t)BATCH * DIM * NPOS;
    char* ws = (char*)d_ws;
    int*      cnt = (int*)(ws + WS_CNT);
    float*    esq = (float*)(ws + WS_ESQ);
    _Float16* wpk = (_Float16*)(ws + WS_WPK);
    float*    wT  = (float*)(ws + WS_WT);
    int*      list = (int*)(ws + WS_LIST);

    prep<<<273, 256, 0, stream>>>(w, wpk, wT, esq, cnt);
    vq_main<<<(BATCH * NPOS) / NPB, 512, 0, stream>>>(x, wpk, esq, wT, quant, argm, cnt, list);
    refine<<<256, 256, 0, stream>>>(x, w, quant, argm, cnt, list);
}